// Round 13
// baseline (55.811 us; speedup 1.0000x reference)
//
#include <hip/hip_runtime.h>
#include <hip/hip_bf16.h>
#include <string.h>

#define NUM_CLASS 4096
#define HIDDEN    512
#define NGROUPS   64
#define BATCH     64

// ws layout (int offsets):
//   [0..127]          chunk flags (zeroed via hipMemsetAsync each call)
//   [10240..18431]    inv[2][4096]   (scatter fallback only)
//   float idx 16384+: tmp[kh][h][class 4096][b 64]
#define WS_INV   10240
#define TMP_OFF_F 16384
#define TMP_H_STRIDE (4096*64)       // floats per (kh,h) slice (1 MiB)
#define TMP_S_STRIDE (2*4096*64)     // floats per kh step (2 MiB)

typedef __attribute__((ext_vector_type(8))) short short8;
typedef __attribute__((ext_vector_type(4))) float f32x4;

__device__ __forceinline__ unsigned int pack2bf(float a, float b) {
    __hip_bfloat16 ha = __float2bfloat16(a), hb = __float2bfloat16(b);
    unsigned short ua, ub;
    memcpy(&ua, &ha, 2); memcpy(&ub, &hb, 2);
    return (unsigned int)ua | ((unsigned int)ub << 16);
}

// scatter-fallback prep: inv permutation
__global__ __launch_bounds__(1024) void prep_inv_kernel(
    const int* __restrict__ co_idx, const int* __restrict__ cl_idx,
    int* __restrict__ ws)
{
    int tid = threadIdx.x;
    for (int v = tid; v < 2 * NUM_CLASS; v += 1024) {
        int h = v >> 12, c = v & (NUM_CLASS - 1);
        const int* idx = h ? cl_idx : co_idx;
        ws[WS_INV + h * NUM_CLASS + idx[c]] = c;
    }
}

// =================== single-kernel producer-consumer ========================
// blocks [0, 128*KS)          : LDS-staged chunk GEMM -> dense tmp + flag
// blocks [128*KS, 128*KS+256) : spin on needed chunk flags -> permute -> out
// No deadlock: producers never wait; queued consumers run after producers
// retire and find flags already set.
template<int KS>
__global__ __launch_bounds__(256, 2) void gwl_pc(
    const float* __restrict__ x,
    const float* __restrict__ co_W, const float* __restrict__ cl_W,
    const float* __restrict__ co_b, const float* __restrict__ cl_b,
    const int* __restrict__ co_gof, const int* __restrict__ cl_gof,
    const int* __restrict__ co_idx, const int* __restrict__ cl_idx,
    int* __restrict__ flags, float* __restrict__ tmp,
    float* __restrict__ out)
{
    __shared__ __align__(16) unsigned char smem[35848];
    int bid = blockIdx.x;
    int tid = threadIdx.x;

    if (bid < 128 * KS) {
        // ---------------- producer: chunk-slot LDS-staged GEMM -------------
        const int NCH = 8 / KS;
        const int nblk = 128 * KS;
        const int chunk = nblk >> 3;
        int swz = (bid & 7) * chunk + (bid >> 3);   // XCD-chunked bijection
        int cid = swz & 63;
        int r1  = swz >> 6;
        int h   = r1 & 1;
        int kh  = r1 >> 1;
        int c0  = cid * 64;

        const float* Wp  = h ? cl_W : co_W;
        const int*   gof = h ? cl_gof : co_gof;

        unsigned short (*Xs)[72]  = (unsigned short(*)[72])smem;
        unsigned short (*Wls)[72] = (unsigned short(*)[72])(smem + 9216);
        float (*ftile)[65]        = (float(*)[65])(smem + 18432);
        int* s_seg_lo = (int*)(smem + 35072);   // 65 ints
        int* s_seg_g  = (int*)(smem + 35332);   // 64 ints (at 35072+260)
        int* s_nseg   = (int*)(smem + 35588);

        int l = tid & 63, w = tid >> 6;

        if (tid < 64) {
            int gi = gof[c0 + tid];
            int prev = (tid == 0) ? -1 : gof[c0 + tid - 1];
            bool is_start = (gi != prev);
            unsigned long long m = __ballot(is_start);
            int segidx = (int)__popcll(m & ((1ull << tid) - 1ull));
            if (is_start) { s_seg_lo[segidx] = tid; s_seg_g[segidx] = gi; }
            if (tid == 0) {
                int ns = (int)__popcll(m);
                *s_nseg = ns;
                s_seg_lo[ns] = 64;
            }
        }

        int rowq[4], kvq[4];
        #pragma unroll
        for (int q = 0; q < 4; ++q) {
            int v = q * 256 + tid;
            rowq[q] = v >> 4;
            kvq[q]  = v & 15;
        }

        float4 rxA[4], rwA[4], rxB[4], rwB[4];
        f32x4 acc[4];
        #pragma unroll
        for (int i = 0; i < 4; ++i) acc[i] = (f32x4)(0.0f);

        const int kbase = kh * (HIDDEN / KS);

#define LOADC(S, RX, RW) do {                                                       \
    int si_ = (S) / NCH, t_ = (S) % NCH;                                            \
    int k0_ = kbase + t_ * 64;                                                      \
    int xr_ = h * 64 + s_seg_g[si_];                                                \
    _Pragma("unroll")                                                               \
    for (int q = 0; q < 4; ++q) {                                                   \
        RX[q] = *(const float4*)(x + rowq[q] * 65536 + xr_ * 512 + k0_ + kvq[q]*4); \
        RW[q] = *(const float4*)(Wp + (c0 + rowq[q]) * 512 + k0_ + kvq[q] * 4);     \
    } } while (0)

#define STOREC(RX, RW) do {                                                         \
    _Pragma("unroll")                                                               \
    for (int q = 0; q < 4; ++q) {                                                   \
        unsigned int x0 = pack2bf(RX[q].x, RX[q].y);                                \
        unsigned int x1 = pack2bf(RX[q].z, RX[q].w);                                \
        *(uint2*)&Xs[rowq[q]][kvq[q] * 4] = make_uint2(x0, x1);                     \
        unsigned int w0 = pack2bf(RW[q].x, RW[q].y);                                \
        unsigned int w1 = pack2bf(RW[q].z, RW[q].w);                                \
        *(uint2*)&Wls[rowq[q]][kvq[q] * 4] = make_uint2(w0, w1);                    \
    } } while (0)

#define COMPUTEC() do {                                                             \
    _Pragma("unroll")                                                               \
    for (int kq = 0; kq < 2; ++kq) {                                                \
        int koff = kq * 32 + (l >> 4) * 8;                                          \
        short8 bfrag = *(const short8*)&Wls[w * 16 + (l & 15)][koff];               \
        _Pragma("unroll")                                                           \
        for (int i = 0; i < 4; ++i) {                                               \
            short8 afrag = *(const short8*)&Xs[16 * i + (l & 15)][koff];            \
            acc[i] = __builtin_amdgcn_mfma_f32_16x16x32_bf16(afrag, bfrag, acc[i],  \
                                                             0, 0, 0);              \
        }                                                                           \
    } } while (0)

        __syncthreads();   // segment data ready
        int nseg = *s_nseg;
        int nsteps = nseg * NCH;
        int slotw = w * 16 + (l & 15);

        LOADC(0, rxA, rwA);
        STOREC(rxA, rwA);
        __syncthreads();

        #pragma unroll 1
        for (int s = 0; s < nsteps; ++s) {
            bool nxt = (s + 1 < nsteps);
            if (nxt) {
                if (s & 1) LOADC(s + 1, rxA, rwA);
                else       LOADC(s + 1, rxB, rwB);
            }
            COMPUTEC();
            if ((s % NCH) == NCH - 1) {
                int si = s / NCH;
                int lo = s_seg_lo[si], hi = s_seg_lo[si + 1];
                if (slotw >= lo && slotw < hi) {
                    #pragma unroll
                    for (int i = 0; i < 4; ++i)
                        #pragma unroll
                        for (int r = 0; r < 4; ++r)
                            ftile[slotw][16 * i + (l >> 4) * 4 + r] = acc[i][r];
                }
                #pragma unroll
                for (int i = 0; i < 4; ++i) acc[i] = (f32x4)(0.0f);
            }
            __syncthreads();
            if (nxt) {
                if (s & 1) STOREC(rxA, rwA);
                else       STOREC(rxB, rwB);
                __syncthreads();
            }
        }

        float* tmph = tmp + (size_t)(kh * 2 + h) * TMP_H_STRIDE;
        #pragma unroll
        for (int p = 0; p < 4; ++p) {
            int f = p * 256 + tid;
            int slot = f >> 4, b4 = (f & 15) * 4;
            *(float4*)&tmph[(size_t)(c0 + slot) * 64 + b4] =
                *(const float4*)&ftile[slot][b4];
        }

        // publish: all stores drained at the barrier; one L2 writeback; then
        // a RELAXED agent RMW on the chunk flag (release via preceding fence).
        __syncthreads();
        if (tid == 0) {
            __threadfence();
            __hip_atomic_fetch_add(&flags[h * 64 + cid], 1,
                                   __ATOMIC_RELAXED, __HIP_MEMORY_SCOPE_AGENT);
        }
#undef LOADC
#undef STOREC
#undef COMPUTEC
    } else {
        // ---------------- consumer: gather-free permute --------------------
        int pb = bid - 128 * KS;          // 0..255
        int jc = pb & 127;                // 32-column chunk
        int h  = pb >> 7;
        const float* bias = h ? cl_b : co_b;
        const int*   idx  = h ? cl_idx : co_idx;
        const float* tmph = tmp + (size_t)h * TMP_H_STRIDE;

        // spin (RELAXED, no cache maintenance) until needed chunks complete
        if (tid < 32) {
            int c = idx[jc * 32 + tid];
            const int* fl = &flags[h * 64 + (c >> 6)];
            while (__hip_atomic_load(fl, __ATOMIC_RELAXED,
                                     __HIP_MEMORY_SCOPE_AGENT) < KS)
                __builtin_amdgcn_s_sleep(8);
        }
        __syncthreads();
        __builtin_amdgcn_fence(__ATOMIC_ACQUIRE, "agent");  // one L2 inv

        float (*tile)[33] = (float(*)[33])smem;
        int lane = tid & 63, w = tid >> 6;

        #pragma unroll
        for (int u = 0; u < 8; ++u) {
            int jj = u * 4 + w;               // 0..31, wave-uniform
            int j  = jc * 32 + jj;
            int c  = idx[j];                  // wave-uniform scalar
            float v = bias[c];
            #pragma unroll
            for (int s = 0; s < KS; ++s)
                v += tmph[(size_t)s * TMP_S_STRIDE + (size_t)c * 64 + lane];
            tile[lane][jj] = v;               // [b][j], stride 33
        }
        __syncthreads();

        #pragma unroll
        for (int p = 0; p < 2; ++p) {
            int f = p * 256 + tid;
            int b = f >> 3, j4 = (f & 7) * 4;
            *(float4*)&out[((size_t)h * 64 + b) * 4096 + jc * 32 + j4] =
                *(const float4*)&tile[b][j4];
        }
    }
}

// ---------------- scatter fallback (tiny ws): proven LDS-staged kernel -----
__global__ __launch_bounds__(256, 4) void gwl_stage1_scatter(
    const float* __restrict__ x,
    const float* __restrict__ co_W, const float* __restrict__ cl_W,
    const float* __restrict__ co_b, const float* __restrict__ cl_b,
    const int* __restrict__ co_gof, const int* __restrict__ cl_gof,
    int* __restrict__ ws, float* __restrict__ out)
{
    const int NCH = 8;
    int bid = blockIdx.x;
    int swz = (bid & 7) * 16 + (bid >> 3);
    int cid = swz & 63;
    int h   = swz >> 6;
    int c0  = cid * 64;

    const float* Wp  = h ? cl_W : co_W;
    const int*   gof = h ? cl_gof : co_gof;

    __shared__ __align__(16) unsigned short Xs[64][72];
    __shared__ __align__(16) unsigned short Wls[64][72];
    __shared__ float ftile[64][65];
    __shared__ int s_seg_lo[65];
    __shared__ int s_seg_g[64];
    __shared__ int s_nseg;

    int tid = threadIdx.x;
    int l = tid & 63, w = tid >> 6;

    if (tid < 64) {
        int gi = gof[c0 + tid];
        int prev = (tid == 0) ? -1 : gof[c0 + tid - 1];
        bool is_start = (gi != prev);
        unsigned long long m = __ballot(is_start);
        int segidx = (int)__popcll(m & ((1ull << tid) - 1ull));
        if (is_start) { s_seg_lo[segidx] = tid; s_seg_g[segidx] = gi; }
        if (tid == 0) {
            int ns = (int)__popcll(m);
            s_nseg = ns;
            s_seg_lo[ns] = 64;
        }
    }

    int rowq[4], kvq[4];
    #pragma unroll
    for (int q = 0; q < 4; ++q) {
        int v = q * 256 + tid;
        rowq[q] = v >> 4;
        kvq[q]  = v & 15;
    }

    float4 rxA[4], rwA[4], rxB[4], rwB[4];
    f32x4 acc[4];
    #pragma unroll
    for (int i = 0; i < 4; ++i) acc[i] = (f32x4)(0.0f);

#define LOADC(S, RX, RW) do {                                                       \
    int si_ = (S) / NCH, t_ = (S) % NCH;                                            \
    int k0_ = t_ * 64;                                                              \
    int xr_ = h * 64 + s_seg_g[si_];                                                \
    _Pragma("unroll")                                                               \
    for (int q = 0; q < 4; ++q) {                                                   \
        RX[q] = *(const float4*)(x + rowq[q] * 65536 + xr_ * 512 + k0_ + kvq[q]*4); \
        RW[q] = *(const float4*)(Wp + (c0 + rowq[q]) * 512 + k0_ + kvq[q] * 4);     \
    } } while (0)

#define STOREC(RX, RW) do {                                                         \
    _Pragma("unroll")                                                               \
    for (int q = 0; q < 4; ++q) {                                                   \
        unsigned int x0 = pack2bf(RX[q].x, RX[q].y);                                \
        unsigned int x1 = pack2bf(RX[q].z, RX[q].w);                                \
        *(uint2*)&Xs[rowq[q]][kvq[q] * 4] = make_uint2(x0, x1);                     \
        unsigned int w0 = pack2bf(RW[q].x, RW[q].y);                                \
        unsigned int w1 = pack2bf(RW[q].z, RW[q].w);                                \
        *(uint2*)&Wls[rowq[q]][kvq[q] * 4] = make_uint2(w0, w1);                    \
    } } while (0)

#define COMPUTEC() do {                                                             \
    _Pragma("unroll")                                                               \
    for (int kq = 0; kq < 2; ++kq) {                                                \
        int koff = kq * 32 + (l >> 4) * 8;                                          \
        short8 bfrag = *(const short8*)&Wls[w * 16 + (l & 15)][koff];               \
        _Pragma("unroll")                                                           \
        for (int i = 0; i < 4; ++i) {                                               \
            short8 afrag = *(const short8*)&Xs[16 * i + (l & 15)][koff];            \
            acc[i] = __builtin_amdgcn_mfma_f32_16x16x32_bf16(afrag, bfrag, acc[i],  \
                                                             0, 0, 0);              \
        }                                                                           \
    } } while (0)

    __syncthreads();
    int nseg = s_nseg;
    int nsteps = nseg * NCH;
    int slotw = w * 16 + (l & 15);

    LOADC(0, rxA, rwA);
    STOREC(rxA, rwA);
    __syncthreads();

    #pragma unroll 1
    for (int s = 0; s < nsteps; ++s) {
        bool nxt = (s + 1 < nsteps);
        if (nxt) {
            if (s & 1) LOADC(s + 1, rxA, rwA);
            else       LOADC(s + 1, rxB, rwB);
        }
        COMPUTEC();
        if ((s % NCH) == NCH - 1) {
            int si = s / NCH;
            int lo = s_seg_lo[si], hi = s_seg_lo[si + 1];
            if (slotw >= lo && slotw < hi) {
                #pragma unroll
                for (int i = 0; i < 4; ++i)
                    #pragma unroll
                    for (int r = 0; r < 4; ++r)
                        ftile[slotw][16 * i + (l >> 4) * 4 + r] = acc[i][r];
            }
            #pragma unroll
            for (int i = 0; i < 4; ++i) acc[i] = (f32x4)(0.0f);
        }
        __syncthreads();
        if (nxt) {
            if (s & 1) STOREC(rxA, rwA);
            else       STOREC(rxB, rwB);
            __syncthreads();
        }
    }

    const float* bias = h ? cl_b : co_b;
    const int*   inv  = ws + WS_INV + h * NUM_CLASS;
    float* outh = out + (size_t)h * BATCH * NUM_CLASS;
    #pragma unroll
    for (int p = 0; p < 4; ++p) {
        int f = p * 256 + tid;
        int slot = f >> 4, b4 = (f & 15) * 4;
        int c = c0 + slot;
        int oc = inv[c];
        float bb = bias[c];
        #pragma unroll
        for (int e = 0; e < 4; ++e)
            outh[(b4 + e) * 4096 + oc] = ftile[slot][b4 + e] + bb;
    }
#undef LOADC
#undef STOREC
#undef COMPUTEC
}

extern "C" void kernel_launch(void* const* d_in, const int* in_sizes, int n_in,
                              void* d_out, int out_size, void* d_ws, size_t ws_size,
                              hipStream_t stream)
{
    (void)in_sizes; (void)n_in; (void)out_size;
    const float* x      = (const float*)d_in[0];
    const float* co_W   = (const float*)d_in[1];
    const float* cl_W   = (const float*)d_in[2];
    const float* co_b   = (const float*)d_in[3];
    const float* cl_b   = (const float*)d_in[4];
    const int*   co_gof = (const int*)d_in[5];
    const int*   cl_gof = (const int*)d_in[6];
    const int*   co_idx = (const int*)d_in[7];
    const int*   cl_idx = (const int*)d_in[8];
    int*   ws  = (int*)d_ws;
    float* tmp = (float*)d_ws + TMP_OFF_F;
    float* out = (float*)d_out;

    const size_t base  = (size_t)TMP_OFF_F * 4;
    const size_t slice = (size_t)TMP_S_STRIDE * 4;   // 2 MiB per kh step

    if (ws_size >= base + 2 * slice) {
        hipMemsetAsync(ws, 0, 512, stream);          // zero chunk flags
        hipLaunchKernelGGL((gwl_pc<2>), dim3(512), dim3(256), 0, stream,
                           x, co_W, cl_W, co_b, cl_b, co_gof, cl_gof,
                           co_idx, cl_idx, ws, tmp, out);
    } else if (ws_size >= base + 1 * slice) {
        hipMemsetAsync(ws, 0, 512, stream);
        hipLaunchKernelGGL((gwl_pc<1>), dim3(384), dim3(256), 0, stream,
                           x, co_W, cl_W, co_b, cl_b, co_gof, cl_gof,
                           co_idx, cl_idx, ws, tmp, out);
    } else {
        hipLaunchKernelGGL(prep_inv_kernel, dim3(1), dim3(1024), 0, stream,
                           co_idx, cl_idx, ws);
        hipLaunchKernelGGL(gwl_stage1_scatter, dim3(128), dim3(256), 0, stream,
                           x, co_W, cl_W, co_b, cl_b, co_gof, cl_gof, ws, out);
    }
}

// Round 14
// 31.676 us; speedup vs baseline: 1.7619x; 1.7619x over previous
//
#include <hip/hip_runtime.h>
#include <hip/hip_bf16.h>
#include <string.h>

#define NUM_CLASS 4096
#define HIDDEN    512
#define NGROUPS   64
#define BATCH     64

// ws layout (int offsets):
//   [10240..18431]    inv[2][4096]   (scatter fallback only)
//   float idx 16384+: tmp[kh][h][class 4096][b 64]
#define WS_INV   10240
#define TMP_OFF_F 16384
#define TMP_H_STRIDE (4096*64)       // floats per (kh,h) slice (1 MiB)
#define TMP_S_STRIDE (2*4096*64)     // floats per kh step (2 MiB)

typedef __attribute__((ext_vector_type(8))) short short8;
typedef __attribute__((ext_vector_type(4))) float f32x4;

__device__ __forceinline__ unsigned int pack2bf(float a, float b) {
    __hip_bfloat16 ha = __float2bfloat16(a), hb = __float2bfloat16(b);
    unsigned short ua, ub;
    memcpy(&ua, &ha, 2); memcpy(&ub, &hb, 2);
    return (unsigned int)ua | ((unsigned int)ub << 16);
}

__device__ __forceinline__ short8 cvt8(float4 a, float4 b) {
    union { short8 s; unsigned int u[4]; } r;
    r.u[0] = pack2bf(a.x, a.y); r.u[1] = pack2bf(a.z, a.w);
    r.u[2] = pack2bf(b.x, b.y); r.u[3] = pack2bf(b.z, b.w);
    return r.s;
}

// scatter-fallback prep: inv permutation
__global__ __launch_bounds__(1024) void prep_inv_kernel(
    const int* __restrict__ co_idx, const int* __restrict__ cl_idx,
    int* __restrict__ ws)
{
    int tid = threadIdx.x;
    for (int v = tid; v < 2 * NUM_CLASS; v += 1024) {
        int h = v >> 12, c = v & (NUM_CLASS - 1);
        const int* idx = h ? cl_idx : co_idx;
        ws[WS_INV + h * NUM_CLASS + idx[c]] = c;
    }
}

// ---------------- primary: direct-from-global MFMA GEMM ---------------------
// block = (class chunk 64, h, kh). No LDS, no syncthreads anywhere. Each wave
// owns 16 classes x ALL 64 batches; per-wave pend loop over the distinct
// groups among its 16 classes (avg ~1.25 passes). W-frag loads and gof load
// issue concurrently at entry; per pass 16 independent float4 loads batched.
template<int KS>
__global__ __launch_bounds__(256, (KS == 1) ? 2 : 4) void gwl_gemm_direct(
    const float* __restrict__ x,
    const float* __restrict__ co_W, const float* __restrict__ cl_W,
    const int* __restrict__ co_gof, const int* __restrict__ cl_gof,
    float* __restrict__ tmp)
{
    const int KQ = 16 / KS;              // MFMA K-steps per block (KQ*32 K)
    const int nblk = 128 * KS;           // 64 chunks * 2 h * KS kh
    const int chunk = nblk >> 3;
    int bid = blockIdx.x;
    int swz = (bid & 7) * chunk + (bid >> 3);   // XCD-chunked bijection
    int cid = swz & 63;
    int r1  = swz >> 6;
    int h   = r1 & 1;
    int kh  = r1 >> 1;
    int c0  = cid * 64;

    const float* Wp  = h ? cl_W : co_W;
    const int*   gof = h ? cl_gof : co_gof;

    int tid = threadIdx.x;
    int l = tid & 63, w = tid >> 6;
    int kcol  = kh * (HIDDEN / KS) + (l >> 4) * 8;  // per-lane K offset
    int crow  = c0 + w * 16 + (l & 15);             // this lane's class row
    int brow  = l & 15;                             // batch base (i adds 16)

    // issue gof load and all W-fragment loads together (independent)
    int gl = gof[crow];                  // group of this lane's class
    short8 bfrag[KQ];
    #pragma unroll
    for (int kq = 0; kq < KQ; ++kq) {
        const float* wp = Wp + (size_t)crow * 512 + kcol + kq * 32;
        bfrag[kq] = cvt8(*(const float4*)wp, *(const float4*)(wp + 4));
    }

    float* tmph = tmp + (size_t)(kh * 2 + h) * TMP_H_STRIDE;

    unsigned int pend = 0xFFFFu;         // slot bits 0..15 (lanes 0-15 pattern)
    while (pend) {
        int slot0 = (int)__builtin_ctz(pend);
        int g = __shfl(gl, slot0);       // wave-uniform group for this pass
        unsigned long long eq = __ballot(gl == g);
        pend &= ~(unsigned int)(eq & 0xFFFFu);

        int xr = h * 64 + g;
        const float* xp = x + (size_t)xr * 512 + kcol;

        f32x4 acc[4];
        #pragma unroll
        for (int i = 0; i < 4; ++i) acc[i] = (f32x4)(0.0f);

        #pragma unroll
        for (int kp = 0; kp < KQ; kp += 2) {
            // batch 16 independent float4 loads (2 kq x 4 i x 2 halves)
            float4 f[16];
            #pragma unroll
            for (int kq2 = 0; kq2 < 2; ++kq2)
                #pragma unroll
                for (int i = 0; i < 4; ++i) {
                    const float* ap = xp + (size_t)(brow + i * 16) * 65536
                                    + (kp + kq2) * 32;
                    f[(kq2 * 4 + i) * 2]     = *(const float4*)ap;
                    f[(kq2 * 4 + i) * 2 + 1] = *(const float4*)(ap + 4);
                }
            #pragma unroll
            for (int kq2 = 0; kq2 < 2; ++kq2)
                #pragma unroll
                for (int i = 0; i < 4; ++i) {
                    short8 af = cvt8(f[(kq2 * 4 + i) * 2],
                                     f[(kq2 * 4 + i) * 2 + 1]);
                    acc[i] = __builtin_amdgcn_mfma_f32_16x16x32_bf16(
                                 af, bfrag[kp + kq2], acc[i], 0, 0, 0);
                }
        }

        if (gl == g) {
            // lane stores batches i*16 + (l>>4)*4 .. +3 of class crow
            float* tr = tmph + (size_t)crow * 64 + (l >> 4) * 4;
            #pragma unroll
            for (int i = 0; i < 4; ++i)
                *(f32x4*)(tr + 16 * i) = acc[i];
        }
    }
}

// gather-free permute: block = 32 output columns x 64 batch (grid 128 x 2).
// idx/bias loads batched up-front (wave-uniform); KS contiguous 256B tmp runs;
// LDS transpose; coalesced out writes.
template<int KS>
__global__ __launch_bounds__(256) void gwl_permute32(
    const float* __restrict__ tmp,
    const float* __restrict__ co_b, const float* __restrict__ cl_b,
    const int* __restrict__ co_idx, const int* __restrict__ cl_idx,
    float* __restrict__ out)
{
    int jc = blockIdx.x;   // 0..127 : 32-column chunk
    int h  = blockIdx.y;   // 0..1
    const float* bias = h ? cl_b : co_b;
    const int*   idx  = h ? cl_idx : co_idx;
    const float* tmph = tmp + (size_t)h * TMP_H_STRIDE;

    __shared__ float tile[64][33];
    int tid = threadIdx.x;
    int lane = tid & 63, w = tid >> 6;

    // batch the 8 wave-uniform idx loads (one RT), then bias
    int cc[8];
    #pragma unroll
    for (int u = 0; u < 8; ++u) cc[u] = idx[jc * 32 + u * 4 + w];
    float bb[8];
    #pragma unroll
    for (int u = 0; u < 8; ++u) bb[u] = bias[cc[u]];

    #pragma unroll
    for (int u = 0; u < 8; ++u) {
        int jj = u * 4 + w;               // 0..31, wave-uniform
        float v = bb[u];
        #pragma unroll
        for (int s = 0; s < KS; ++s)
            v += tmph[(size_t)s * TMP_S_STRIDE + (size_t)cc[u] * 64 + lane];
        tile[lane][jj] = v;               // [b][j], stride 33 -> conflict-free
    }
    __syncthreads();

    #pragma unroll
    for (int p = 0; p < 2; ++p) {
        int f = p * 256 + tid;
        int b = f >> 3, j4 = (f & 7) * 4;
        *(float4*)&out[((size_t)h * 64 + b) * 4096 + jc * 32 + j4] =
            *(const float4*)&tile[b][j4];
    }
}

// ---------------- scatter fallback (tiny ws): proven LDS-staged kernel -----
__global__ __launch_bounds__(256, 4) void gwl_stage1_scatter(
    const float* __restrict__ x,
    const float* __restrict__ co_W, const float* __restrict__ cl_W,
    const float* __restrict__ co_b, const float* __restrict__ cl_b,
    const int* __restrict__ co_gof, const int* __restrict__ cl_gof,
    int* __restrict__ ws, float* __restrict__ out)
{
    const int NCH = 8;
    int bid = blockIdx.x;
    int swz = (bid & 7) * 16 + (bid >> 3);
    int cid = swz & 63;
    int h   = swz >> 6;
    int c0  = cid * 64;

    const float* Wp  = h ? cl_W : co_W;
    const int*   gof = h ? cl_gof : co_gof;

    __shared__ __align__(16) unsigned short Xs[64][72];
    __shared__ __align__(16) unsigned short Wls[64][72];
    __shared__ float ftile[64][65];
    __shared__ int s_seg_lo[65];
    __shared__ int s_seg_g[64];
    __shared__ int s_nseg;

    int tid = threadIdx.x;
    int l = tid & 63, w = tid >> 6;

    if (tid < 64) {
        int gi = gof[c0 + tid];
        int prev = (tid == 0) ? -1 : gof[c0 + tid - 1];
        bool is_start = (gi != prev);
        unsigned long long m = __ballot(is_start);
        int segidx = (int)__popcll(m & ((1ull << tid) - 1ull));
        if (is_start) { s_seg_lo[segidx] = tid; s_seg_g[segidx] = gi; }
        if (tid == 0) {
            int ns = (int)__popcll(m);
            s_nseg = ns;
            s_seg_lo[ns] = 64;
        }
    }

    int rowq[4], kvq[4];
    #pragma unroll
    for (int q = 0; q < 4; ++q) {
        int v = q * 256 + tid;
        rowq[q] = v >> 4;
        kvq[q]  = v & 15;
    }

    float4 rxA[4], rwA[4], rxB[4], rwB[4];
    f32x4 acc[4];
    #pragma unroll
    for (int i = 0; i < 4; ++i) acc[i] = (f32x4)(0.0f);

#define LOADC(S, RX, RW) do {                                                       \
    int si_ = (S) / NCH, t_ = (S) % NCH;                                            \
    int k0_ = t_ * 64;                                                              \
    int xr_ = h * 64 + s_seg_g[si_];                                                \
    _Pragma("unroll")                                                               \
    for (int q = 0; q < 4; ++q) {                                                   \
        RX[q] = *(const float4*)(x + rowq[q] * 65536 + xr_ * 512 + k0_ + kvq[q]*4); \
        RW[q] = *(const float4*)(Wp + (c0 + rowq[q]) * 512 + k0_ + kvq[q] * 4);     \
    } } while (0)

#define STOREC(RX, RW) do {                                                         \
    _Pragma("unroll")                                                               \
    for (int q = 0; q < 4; ++q) {                                                   \
        unsigned int x0 = pack2bf(RX[q].x, RX[q].y);                                \
        unsigned int x1 = pack2bf(RX[q].z, RX[q].w);                                \
        *(uint2*)&Xs[rowq[q]][kvq[q] * 4] = make_uint2(x0, x1);                     \
        unsigned int w0 = pack2bf(RW[q].x, RW[q].y);                                \
        unsigned int w1 = pack2bf(RW[q].z, RW[q].w);                                \
        *(uint2*)&Wls[rowq[q]][kvq[q] * 4] = make_uint2(w0, w1);                    \
    } } while (0)

#define COMPUTEC() do {                                                             \
    _Pragma("unroll")                                                               \
    for (int kq = 0; kq < 2; ++kq) {                                                \
        int koff = kq * 32 + (l >> 4) * 8;                                          \
        short8 bfrag = *(const short8*)&Wls[w * 16 + (l & 15)][koff];               \
        _Pragma("unroll")                                                           \
        for (int i = 0; i < 4; ++i) {                                               \
            short8 afrag = *(const short8*)&Xs[16 * i + (l & 15)][koff];            \
            acc[i] = __builtin_amdgcn_mfma_f32_16x16x32_bf16(afrag, bfrag, acc[i],  \
                                                             0, 0, 0);              \
        }                                                                           \
    } } while (0)

    __syncthreads();
    int nseg = s_nseg;
    int nsteps = nseg * NCH;
    int slotw = w * 16 + (l & 15);

    LOADC(0, rxA, rwA);
    STOREC(rxA, rwA);
    __syncthreads();

    #pragma unroll 1
    for (int s = 0; s < nsteps; ++s) {
        bool nxt = (s + 1 < nsteps);
        if (nxt) {
            if (s & 1) LOADC(s + 1, rxA, rwA);
            else       LOADC(s + 1, rxB, rwB);
        }
        COMPUTEC();
        if ((s % NCH) == NCH - 1) {
            int si = s / NCH;
            int lo = s_seg_lo[si], hi = s_seg_lo[si + 1];
            if (slotw >= lo && slotw < hi) {
                #pragma unroll
                for (int i = 0; i < 4; ++i)
                    #pragma unroll
                    for (int r = 0; r < 4; ++r)
                        ftile[slotw][16 * i + (l >> 4) * 4 + r] = acc[i][r];
            }
            #pragma unroll
            for (int i = 0; i < 4; ++i) acc[i] = (f32x4)(0.0f);
        }
        __syncthreads();
        if (nxt) {
            if (s & 1) STOREC(rxA, rwA);
            else       STOREC(rxB, rwB);
            __syncthreads();
        }
    }

    const float* bias = h ? cl_b : co_b;
    const int*   inv  = ws + WS_INV + h * NUM_CLASS;
    float* outh = out + (size_t)h * BATCH * NUM_CLASS;
    #pragma unroll
    for (int p = 0; p < 4; ++p) {
        int f = p * 256 + tid;
        int slot = f >> 4, b4 = (f & 15) * 4;
        int c = c0 + slot;
        int oc = inv[c];
        float bb = bias[c];
        #pragma unroll
        for (int e = 0; e < 4; ++e)
            outh[(b4 + e) * 4096 + oc] = ftile[slot][b4 + e] + bb;
    }
#undef LOADC
#undef STOREC
#undef COMPUTEC
}

extern "C" void kernel_launch(void* const* d_in, const int* in_sizes, int n_in,
                              void* d_out, int out_size, void* d_ws, size_t ws_size,
                              hipStream_t stream)
{
    (void)in_sizes; (void)n_in; (void)out_size;
    const float* x      = (const float*)d_in[0];
    const float* co_W   = (const float*)d_in[1];
    const float* cl_W   = (const float*)d_in[2];
    const float* co_b   = (const float*)d_in[3];
    const float* cl_b   = (const float*)d_in[4];
    const int*   co_gof = (const int*)d_in[5];
    const int*   cl_gof = (const int*)d_in[6];
    const int*   co_idx = (const int*)d_in[7];
    const int*   cl_idx = (const int*)d_in[8];
    int*   ws  = (int*)d_ws;
    float* tmp = (float*)d_ws + TMP_OFF_F;
    float* out = (float*)d_out;

    const size_t base  = (size_t)TMP_OFF_F * 4;
    const size_t slice = (size_t)TMP_S_STRIDE * 4;   // 2 MiB per kh step

    if (ws_size >= base + 4 * slice) {
        hipLaunchKernelGGL((gwl_gemm_direct<4>), dim3(512), dim3(256), 0, stream,
                           x, co_W, cl_W, co_gof, cl_gof, tmp);
        hipLaunchKernelGGL((gwl_permute32<4>), dim3(128, 2), dim3(256), 0, stream,
                           tmp, co_b, cl_b, co_idx, cl_idx, out);
    } else if (ws_size >= base + 2 * slice) {
        hipLaunchKernelGGL((gwl_gemm_direct<2>), dim3(256), dim3(256), 0, stream,
                           x, co_W, cl_W, co_gof, cl_gof, tmp);
        hipLaunchKernelGGL((gwl_permute32<2>), dim3(128, 2), dim3(256), 0, stream,
                           tmp, co_b, cl_b, co_idx, cl_idx, out);
    } else if (ws_size >= base + 1 * slice) {
        hipLaunchKernelGGL((gwl_gemm_direct<1>), dim3(128), dim3(256), 0, stream,
                           x, co_W, cl_W, co_gof, cl_gof, tmp);
        hipLaunchKernelGGL((gwl_permute32<1>), dim3(128, 2), dim3(256), 0, stream,
                           tmp, co_b, cl_b, co_idx, cl_idx, out);
    } else {
        hipLaunchKernelGGL(prep_inv_kernel, dim3(1), dim3(1024), 0, stream,
                           co_idx, cl_idx, ws);
        hipLaunchKernelGGL(gwl_stage1_scatter, dim3(128), dim3(256), 0, stream,
                           x, co_W, cl_W, co_b, cl_b, co_gof, cl_gof, ws, out);
    }
}